// Round 1
// baseline (764.082 us; speedup 1.0000x reference)
//
#include <hip/hip_runtime.h>
#include <math.h>

#ifndef M_PI
#define M_PI 3.14159265358979323846
#endif

namespace {

constexpr int NF = 128;   // feature width
constexpr int NM = 25;    // total m components (l=0..4)

// ================= compile-time real Clebsch-Gordan tables =================
struct CD { double re, im; };
constexpr CD cmulc(CD x, CD y){ return CD{x.re*y.re - x.im*y.im, x.re*y.im + x.im*y.re}; }

constexpr double cfact(int n){ double r = 1.0; for (int i = 2; i <= n; ++i) r *= (double)i; return r; }

constexpr double csqrt_(double x){
  if (x <= 0.0) return 0.0;
  double g = x < 1.0 ? 1.0 : x;
  for (int i = 0; i < 48; ++i) g = 0.5 * (g + x / g);
  return g;
}

constexpr double cgc_(int l1, int l2, int l3, int m1, int m2, int m3){
  if (m1 + m2 != m3) return 0.0;
  int dmin = l1 > l2 ? l1 - l2 : l2 - l1;
  if (l3 < dmin || l3 > l1 + l2) return 0.0;
  double pre = csqrt_((2.0*l3 + 1.0) * cfact(l3 + l1 - l2) * cfact(l3 - l1 + l2) *
                      cfact(l1 + l2 - l3) / cfact(l1 + l2 + l3 + 1));
  pre *= csqrt_(cfact(l3 + m3) * cfact(l3 - m3) * cfact(l1 - m1) * cfact(l1 + m1) *
                cfact(l2 - m2) * cfact(l2 + m2));
  double s = 0.0;
  for (int k = 0; k <= l1 + l2 - l3; ++k){
    int a0 = k, a1 = l1 + l2 - l3 - k, a2 = l1 - m1 - k;
    int a3 = l2 + m2 - k, a4 = l3 - l2 + m1 + k, a5 = l3 - l1 - m2 + k;
    if (a0 < 0 || a1 < 0 || a2 < 0 || a3 < 0 || a4 < 0 || a5 < 0) continue;
    double d = cfact(a0)*cfact(a1)*cfact(a2)*cfact(a3)*cfact(a4)*cfact(a5);
    s += ((k & 1) ? -1.0 : 1.0) / d;
  }
  return pre * s;
}

// U[a][A]: complex->real SH change of basis, rows indexed by complex m (a=l+m),
// cols by real index A. Mirrors the reference _umat exactly.
constexpr CD umat(int l, int a, int A){
  const double is2 = 0.70710678118654752440;
  int ma = a - l, mA = A - l;
  if (ma == 0) return (mA == 0) ? CD{1.0, 0.0} : CD{0.0, 0.0};
  if (ma > 0){
    double sg = (ma & 1) ? -1.0 : 1.0;
    if (mA ==  ma) return CD{sg * is2, 0.0};
    if (mA == -ma) return CD{0.0, sg * is2};
    return CD{0.0, 0.0};
  }
  if (mA == -ma) return CD{is2, 0.0};
  if (mA ==  ma) return CD{0.0, -is2};
  return CD{0.0, 0.0};
}

struct TpEntry { int a, b, c, p; float v; };
struct TpTable { TpEntry e[1024]; int n; int npaths; };

constexpr TpTable build_tp(){
  TpTable T{};
  T.n = 0;
  int p = 0;
  for (int l1 = 0; l1 < 3; ++l1)
  for (int l2 = 0; l2 < 5; ++l2)
  for (int l3 = 0; l3 < 5; ++l3){
    int dmin = l1 > l2 ? l1 - l2 : l2 - l1;
    if (l3 < dmin || l3 > l1 + l2) continue;
    if ((l1 + l2 + l3) & 1) continue;
    double Cr[5][9][9] = {};
    for (int a = 0; a <= 2*l1; ++a)
    for (int b = 0; b <= 2*l2; ++b){
      int m1 = a - l1, m2 = b - l2, m3 = m1 + m2;
      if (m3 < -l3 || m3 > l3) continue;
      double cg = cgc_(l1, l2, l3, m1, m2, m3);
      if (cg == 0.0) continue;
      int c3 = l3 + m3;
      int Al[2] = { l1 + m1, l1 - m1 }; int nA = (m1 == 0) ? 1 : 2;
      int Bl[2] = { l2 + m2, l2 - m2 }; int nB = (m2 == 0) ? 1 : 2;
      int Cl[2] = { l3 + m3, l3 - m3 }; int nC = (m3 == 0) ? 1 : 2;
      for (int ia = 0; ia < nA; ++ia)
      for (int ib = 0; ib < nB; ++ib)
      for (int ic = 0; ic < nC; ++ic){
        CD u1 = umat(l1, a, Al[ia]);
        CD u2 = umat(l2, b, Bl[ib]);
        CD u3 = umat(l3, c3, Cl[ic]);      // conjugated below
        CD t12 = cmulc(u1, u2);
        double re = t12.re * u3.re + t12.im * u3.im;   // Re(t12 * conj(u3))
        Cr[Al[ia]][Bl[ib]][Cl[ic]] += cg * re;
      }
    }
    for (int A = 0; A <= 2*l1; ++A)
    for (int B = 0; B <= 2*l2; ++B)
    for (int Cc = 0; Cc <= 2*l3; ++Cc){
      double v = Cr[A][B][Cc];
      if (v > 1e-12 || v < -1e-12){
        T.e[T.n].a = l1*l1 + A;
        T.e[T.n].b = l2*l2 + B;
        T.e[T.n].c = l3*l3 + Cc;
        T.e[T.n].p = p;
        T.e[T.n].v = (float)v;
        ++T.n;
      }
    }
    ++p;
  }
  T.npaths = p;
  return T;
}

constexpr TpTable TPT = build_tp();
constexpr int TPN      = TPT.n;
constexpr int NPATHS_C = TPT.npaths;
static_assert(NPATHS_C == 23, "path count mismatch vs reference PATHS");
static_assert(TPN <= 1024, "TP table overflow");

// ================= shared small-GEMM helper =================
// acc[c][m] += sum_f lds[m][f] * W[l(m)][f][g_c], 64 threads, G=2 columns/thread.
__device__ __forceinline__ void dense25(const float* __restrict__ W,
                                        const float* lds,
                                        int g0, int g1,
                                        float acc[2][NM]){
  #pragma unroll
  for (int l = 0; l < 5; ++l){
    const int mb = l * l;
    const int nm = 2 * l + 1;
    const float* Wl = W + l * NF * NF;
    for (int f4 = 0; f4 < NF / 4; ++f4){
      float tv[9][4];
      #pragma unroll
      for (int m = 0; m < nm; ++m){
        float4 v = *(const float4*)&lds[(mb + m) * NF + 4 * f4];
        tv[m][0] = v.x; tv[m][1] = v.y; tv[m][2] = v.z; tv[m][3] = v.w;
      }
      #pragma unroll
      for (int q = 0; q < 4; ++q){
        const float wa = Wl[(4 * f4 + q) * NF + g0];
        const float wb = Wl[(4 * f4 + q) * NF + g1];
        #pragma unroll
        for (int m = 0; m < nm; ++m){
          acc[0][mb + m] = fmaf(tv[m][q], wa, acc[0][mb + m]);
          acc[1][mb + m] = fmaf(tv[m][q], wb, acc[1][mb + m]);
        }
      }
    }
  }
}

// ================= kernel A: per-atom Z = edense_nobias(A, W1) =================
__global__ __launch_bounds__(64) void atoms_kernel(const float* __restrict__ A,
                                                   const float* __restrict__ W1,
                                                   float* __restrict__ Z){
  __shared__ float a_lds[NM * NF];
  const int n    = blockIdx.x;
  const int lane = threadIdx.x;
  const float* Ab = A + (size_t)n * NM * NF;
  #pragma unroll
  for (int m = 0; m < NM; ++m){
    a_lds[m * NF + lane]      = Ab[m * NF + lane];
    a_lds[m * NF + lane + 64] = Ab[m * NF + lane + 64];
  }
  __syncthreads();
  const int g0 = lane, g1 = lane + 64;
  float acc[2][NM];
  #pragma unroll
  for (int c = 0; c < 2; ++c)
    #pragma unroll
    for (int m = 0; m < NM; ++m) acc[c][m] = 0.f;

  dense25(W1, a_lds, g0, g1, acc);

  float* Zb = Z + (size_t)n * NM * NF;
  #pragma unroll
  for (int m = 0; m < NM; ++m){
    Zb[m * NF + g0] = acc[0][m];
    Zb[m * NF + g1] = acc[1][m];
  }
}

// ================= kernel B: per-edge fused pipeline =================
__global__ __launch_bounds__(64) void edge_kernel(const float* __restrict__ Z,
                                                  const int*   __restrict__ nbr,
                                                  const float* __restrict__ disp,
                                                  const float* __restrict__ b1,
                                                  const float* __restrict__ W2,
                                                  const float* __restrict__ b2,
                                                  const float* __restrict__ W3,
                                                  const float* __restrict__ b3,
                                                  const float* __restrict__ wtp,
                                                  float* __restrict__ out){
  __shared__ float t_lds[NM * NF];
  __shared__ float rad_lds[NF];
  const int e    = blockIdx.x;
  const int lane = threadIdx.x;
  const int i = nbr[2 * e], j = nbr[2 * e + 1];
  const float* Zi = Z + (size_t)i * NM * NF;
  const float* Zj = Z + (size_t)j * NM * NF;

  // ---- phase 1: gather+add, normalize, gated mish -> t in LDS ----
  #pragma unroll
  for (int c = 0; c < 2; ++c){
    const int f = lane + 64 * c;
    float y[NM];
    #pragma unroll
    for (int m = 0; m < NM; ++m) y[m] = Zi[m * NF + f] + Zj[m * NF + f];
    y[0] += b1[f];
    float n2 = 0.f;
    #pragma unroll
    for (int m = 0; m < NM; ++m) n2 = fmaf(y[m], y[m], n2);
    const float inv = 1.0f / sqrtf(n2 + 1e-6f);
    #pragma unroll
    for (int m = 0; m < NM; ++m) y[m] *= inv;
    const float s   = y[0];
    const float sp  = fmaxf(s, 0.f) + log1pf(expf(-fabsf(s)));
    const float th  = tanhf(sp);
    const float sig = 1.0f / (1.0f + expf(-s));
    const float dm  = th + s * (1.f - th * th) * sig;
    t_lds[0 * NF + f] = s * th;
    #pragma unroll
    for (int m = 1; m < NM; ++m) t_lds[m * NF + f] = y[m] * dm;
  }
  __syncthreads();

  // ---- phase 2: y2 = edense(t, W2, b2) + t ----
  const int g0 = lane, g1 = lane + 64;
  float acc[2][NM];
  #pragma unroll
  for (int c = 0; c < 2; ++c)
    #pragma unroll
    for (int m = 0; m < NM; ++m) acc[c][m] = 0.f;

  dense25(W2, t_lds, g0, g1, acc);

  acc[0][0] += b2[g0];
  acc[1][0] += b2[g1];
  #pragma unroll
  for (int m = 0; m < NM; ++m){
    acc[0][m] += t_lds[m * NF + g0];
    acc[1][m] += t_lds[m * NF + g1];
  }

  // ---- phase 3: basis expansion + W3 ----
  const float dx = disp[3 * e], dy = disp[3 * e + 1], dz = disp[3 * e + 2];
  const float r  = sqrtf(dx * dx + dy * dy + dz * dz + 1e-12f);
  const float ux = dx / r, uy = dy / r, uz = dz / r;
  const float ang = (float)M_PI * r / 5.0f;
  const float uc = r / 5.0f;
  const float den = fmaxf(1.f - uc * uc, 1e-9f);
  const float cut = (uc < 1.f) ? expf(1.f - 1.f / den) : 0.f;
  rad_lds[lane]      = cosf((float)lane * ang) * cut;
  rad_lds[lane + 64] = cosf((float)(lane + 64) * ang) * cut;
  __syncthreads();

  float rw[3][2] = {{0.f,0.f},{0.f,0.f},{0.f,0.f}};
  for (int f4 = 0; f4 < NF / 4; ++f4){
    float4 v = *(const float4*)&rad_lds[4 * f4];
    float rq[4] = { v.x, v.y, v.z, v.w };
    #pragma unroll
    for (int q = 0; q < 4; ++q){
      const int f = 4 * f4 + q;
      #pragma unroll
      for (int l = 0; l < 3; ++l){
        const float wa = W3[(l * NF + f) * NF + g0];
        const float wb = W3[(l * NF + f) * NF + g1];
        rw[l][0] = fmaf(rq[q], wa, rw[l][0]);
        rw[l][1] = fmaf(rq[q], wb, rw[l][1]);
      }
    }
  }

  const float s3  = 1.7320508075688772f;
  const float sh4 = s3 * ux * uy;
  const float sh5 = s3 * uy * uz;
  const float sh6 = 0.5f * (3.f * uz * uz - 1.f);
  const float sh7 = s3 * ux * uz;
  const float sh8 = 0.5f * s3 * (ux * ux - uy * uy);

  // ---- phase 4+5: tensor product (fully unrolled) + store ----
  #pragma unroll
  for (int c = 0; c < 2; ++c){
    const int g = lane + 64 * c;
    float bd[9];
    bd[0] = rw[0][c] + b3[g];
    bd[1] = uy  * rw[1][c];
    bd[2] = uz  * rw[1][c];
    bd[3] = ux  * rw[1][c];
    bd[4] = sh4 * rw[2][c];
    bd[5] = sh5 * rw[2][c];
    bd[6] = sh6 * rw[2][c];
    bd[7] = sh7 * rw[2][c];
    bd[8] = sh8 * rw[2][c];

    float wp[NPATHS_C];
    #pragma unroll
    for (int p = 0; p < NPATHS_C; ++p) wp[p] = wtp[p * NF + g];

    float o[NM];
    #pragma unroll
    for (int m = 0; m < NM; ++m) o[m] = 0.f;

    #pragma unroll
    for (int t = 0; t < TPN; ++t){
      o[TPT.e[t].c] = fmaf(TPT.e[t].v * wp[TPT.e[t].p],
                           bd[TPT.e[t].a] * acc[c][TPT.e[t].b],
                           o[TPT.e[t].c]);
    }

    float* ob = out + (size_t)e * NM * NF;
    #pragma unroll
    for (int m = 0; m < NM; ++m) ob[m * NF + g] = o[m];
  }
}

} // anonymous namespace

extern "C" void kernel_launch(void* const* d_in, const int* in_sizes, int n_in,
                              void* d_out, int out_size, void* d_ws, size_t ws_size,
                              hipStream_t stream) {
  (void)n_in; (void)out_size;
  const float* A    = (const float*)d_in[0];
  const int*   nbr  = (const int*)  d_in[1];
  const float* disp = (const float*)d_in[2];
  const float* W1   = (const float*)d_in[3];
  const float* b1   = (const float*)d_in[4];
  const float* W2   = (const float*)d_in[5];
  const float* b2   = (const float*)d_in[6];
  const float* W3   = (const float*)d_in[7];
  const float* b3   = (const float*)d_in[8];
  const float* wtp  = (const float*)d_in[9];
  float* out = (float*)d_out;

  const int n_atoms = in_sizes[0] / (NM * NF);
  const int n_edges = in_sizes[1] / 2;

  if (ws_size < (size_t)n_atoms * NM * NF * sizeof(float)) return;  // need 52.4 MB scratch
  float* Z = (float*)d_ws;

  atoms_kernel<<<dim3(n_atoms), dim3(64), 0, stream>>>(A, W1, Z);
  edge_kernel<<<dim3(n_edges), dim3(64), 0, stream>>>(Z, nbr, disp, b1, W2, b2, W3, b3, wtp, out);
}

// Round 2
// 751.525 us; speedup vs baseline: 1.0167x; 1.0167x over previous
//
#include <hip/hip_runtime.h>
#include <math.h>

#ifndef M_PI
#define M_PI 3.14159265358979323846
#endif

namespace {

constexpr int NF = 128;   // feature width
constexpr int NM = 25;    // total m components (l=0..4)

// ================= compile-time real Clebsch-Gordan tables =================
struct CD { double re, im; };
constexpr CD cmulc(CD x, CD y){ return CD{x.re*y.re - x.im*y.im, x.re*y.im + x.im*y.re}; }

constexpr double cfact(int n){ double r = 1.0; for (int i = 2; i <= n; ++i) r *= (double)i; return r; }

constexpr double csqrt_(double x){
  if (x <= 0.0) return 0.0;
  double g = x < 1.0 ? 1.0 : x;
  for (int i = 0; i < 48; ++i) g = 0.5 * (g + x / g);
  return g;
}

constexpr double cgc_(int l1, int l2, int l3, int m1, int m2, int m3){
  if (m1 + m2 != m3) return 0.0;
  int dmin = l1 > l2 ? l1 - l2 : l2 - l1;
  if (l3 < dmin || l3 > l1 + l2) return 0.0;
  double pre = csqrt_((2.0*l3 + 1.0) * cfact(l3 + l1 - l2) * cfact(l3 - l1 + l2) *
                      cfact(l1 + l2 - l3) / cfact(l1 + l2 + l3 + 1));
  pre *= csqrt_(cfact(l3 + m3) * cfact(l3 - m3) * cfact(l1 - m1) * cfact(l1 + m1) *
                cfact(l2 - m2) * cfact(l2 + m2));
  double s = 0.0;
  for (int k = 0; k <= l1 + l2 - l3; ++k){
    int a0 = k, a1 = l1 + l2 - l3 - k, a2 = l1 - m1 - k;
    int a3 = l2 + m2 - k, a4 = l3 - l2 + m1 + k, a5 = l3 - l1 - m2 + k;
    if (a0 < 0 || a1 < 0 || a2 < 0 || a3 < 0 || a4 < 0 || a5 < 0) continue;
    double d = cfact(a0)*cfact(a1)*cfact(a2)*cfact(a3)*cfact(a4)*cfact(a5);
    s += ((k & 1) ? -1.0 : 1.0) / d;
  }
  return pre * s;
}

constexpr CD umat(int l, int a, int A){
  const double is2 = 0.70710678118654752440;
  int ma = a - l, mA = A - l;
  if (ma == 0) return (mA == 0) ? CD{1.0, 0.0} : CD{0.0, 0.0};
  if (ma > 0){
    double sg = (ma & 1) ? -1.0 : 1.0;
    if (mA ==  ma) return CD{sg * is2, 0.0};
    if (mA == -ma) return CD{0.0, sg * is2};
    return CD{0.0, 0.0};
  }
  if (mA == -ma) return CD{is2, 0.0};
  if (mA ==  ma) return CD{0.0, -is2};
  return CD{0.0, 0.0};
}

struct TpEntry { int a, b, c, p; float v; };
struct TpTable { TpEntry e[1024]; int n; int npaths; };

constexpr TpTable build_tp(){
  TpTable T{};
  T.n = 0;
  int p = 0;
  for (int l1 = 0; l1 < 3; ++l1)
  for (int l2 = 0; l2 < 5; ++l2)
  for (int l3 = 0; l3 < 5; ++l3){
    int dmin = l1 > l2 ? l1 - l2 : l2 - l1;
    if (l3 < dmin || l3 > l1 + l2) continue;
    if ((l1 + l2 + l3) & 1) continue;
    double Cr[5][9][9] = {};
    for (int a = 0; a <= 2*l1; ++a)
    for (int b = 0; b <= 2*l2; ++b){
      int m1 = a - l1, m2 = b - l2, m3 = m1 + m2;
      if (m3 < -l3 || m3 > l3) continue;
      double cg = cgc_(l1, l2, l3, m1, m2, m3);
      if (cg == 0.0) continue;
      int c3 = l3 + m3;
      int Al[2] = { l1 + m1, l1 - m1 }; int nA = (m1 == 0) ? 1 : 2;
      int Bl[2] = { l2 + m2, l2 - m2 }; int nB = (m2 == 0) ? 1 : 2;
      int Cl[2] = { l3 + m3, l3 - m3 }; int nC = (m3 == 0) ? 1 : 2;
      for (int ia = 0; ia < nA; ++ia)
      for (int ib = 0; ib < nB; ++ib)
      for (int ic = 0; ic < nC; ++ic){
        CD u1 = umat(l1, a, Al[ia]);
        CD u2 = umat(l2, b, Bl[ib]);
        CD u3 = umat(l3, c3, Cl[ic]);
        CD t12 = cmulc(u1, u2);
        double re = t12.re * u3.re + t12.im * u3.im;   // Re(t12 * conj(u3))
        Cr[Al[ia]][Bl[ib]][Cl[ic]] += cg * re;
      }
    }
    for (int A = 0; A <= 2*l1; ++A)
    for (int B = 0; B <= 2*l2; ++B)
    for (int Cc = 0; Cc <= 2*l3; ++Cc){
      double v = Cr[A][B][Cc];
      if (v > 1e-12 || v < -1e-12){
        T.e[T.n].a = l1*l1 + A;
        T.e[T.n].b = l2*l2 + B;
        T.e[T.n].c = l3*l3 + Cc;
        T.e[T.n].p = p;
        T.e[T.n].v = (float)v;
        ++T.n;
      }
    }
    ++p;
  }
  T.npaths = p;
  return T;
}

constexpr TpTable TPT = build_tp();
constexpr int TPN      = TPT.n;
constexpr int NPATHS_C = TPT.npaths;
static_assert(NPATHS_C == 23, "path count mismatch vs reference PATHS");
static_assert(TPN <= 1024, "TP table overflow");

// Sorted copy: grouped by (c<13 ? 0 : 1) major, then by b ascending (enables
// register-caching of y2[b] in the unrolled TP loop, and wave-uniform halves).
struct TpSorted { TpEntry e[1024]; int n; int split; };
constexpr TpSorted sort_tp(){
  TpSorted S{}; S.n = TPT.n; S.split = 0;
  int k = 0;
  for (int half = 0; half < 2; ++half){
    for (int b = 0; b < NM; ++b)
      for (int t = 0; t < TPT.n; ++t){
        int h = (TPT.e[t].c >= 13) ? 1 : 0;
        if (h == half && TPT.e[t].b == b) S.e[k++] = TPT.e[t];
      }
    if (half == 0) S.split = k;
  }
  return S;
}
constexpr TpSorted STP = sort_tp();
static_assert(STP.n == TPN, "sort lost entries");
constexpr int TP_SPLIT = STP.split;

// ================= MFMA helpers =================
using bfrag = __attribute__((ext_vector_type(8))) short;   // 8 bf16
using f32x4 = __attribute__((ext_vector_type(4))) float;

__device__ __forceinline__ unsigned short bf16rn(float x){
  unsigned u = __float_as_uint(x);
  unsigned r = (u + 0x7FFFu + ((u >> 16) & 1u)) >> 16;
  return (unsigned short)r;
}
__device__ __forceinline__ float bfhi_to_f(unsigned short h){
  return __uint_as_float((unsigned)h << 16);
}

constexpr int T_STRIDE = 136;  // bf16 elements per padded t-row (breaks A-frag bank conflicts)
constexpr int Y_STRIDE = 129;  // fp32 elements per padded y2 row

// ================= prep kernel: swizzle W1/W2 into B-fragment order, bf16 hi/lo ==========
// B-frag for mfma_f32_16x16x32_bf16: lane L holds B[k = 8*(L>>4)+j][n = L&15], j=0..7.
// Frag id = (l*8 + nt)*4 + ks ; element offset = frag*512 + L*8 + j (shorts).
__global__ __launch_bounds__(256) void prep_kernel(const float* __restrict__ W1,
                                                   const float* __restrict__ W2,
                                                   short* __restrict__ W1hi, short* __restrict__ W1lo,
                                                   short* __restrict__ W2hi, short* __restrict__ W2lo){
  const int t = blockIdx.x * 256 + threadIdx.x;      // 0 .. 20479
  const int arr  = t / 10240;                        // 0: W1, 1: W2
  const int s    = t % 10240;
  const int lane = s & 63;
  const int ks   = (s >> 6) & 3;
  const int nt   = (s >> 8) & 7;
  const int l    = s >> 11;                          // 0..4
  const float* W = arr ? W2 : W1;
  short* Hi = arr ? W2hi : W1hi;
  short* Lo = arr ? W2lo : W1lo;
  const int g = 16 * nt + (lane & 15);
  short hi8[8], lo8[8];
  #pragma unroll
  for (int j = 0; j < 8; ++j){
    const int f = 32 * ks + 8 * (lane >> 4) + j;
    const float w = W[(l * NF + f) * NF + g];
    unsigned short h = bf16rn(w);
    hi8[j] = (short)h;
    lo8[j] = (short)bf16rn(w - bfhi_to_f(h));
  }
  const size_t off = (size_t)s * 8;
  *(bfrag*)(Hi + off) = *(bfrag*)hi8;
  *(bfrag*)(Lo + off) = *(bfrag*)lo8;
}

// ================= shared GEMM body =================
// Computes acc[l][n2] (16x16 C-tiles) = t(hi+lo) @ W(hi+lo), per-l padded tiles.
// tHi/tLo: LDS, padded rows (32 x T_STRIDE). Whi/Wlo: swizzled global.
__device__ __forceinline__ void mfma_gemm(const unsigned short* tHi, const unsigned short* tLo,
                                          const short* __restrict__ Whi, const short* __restrict__ Wlo,
                                          int lane, int wave, f32x4 acc[5][2]){
  const int quad = lane >> 4, l16 = lane & 15;
  #pragma unroll
  for (int l = 0; l < 5; ++l){
    const int mb = l * l;
    #pragma unroll
    for (int ks = 0; ks < 4; ++ks){
      const bfrag ah = *(const bfrag*)&tHi[(mb + l16) * T_STRIDE + 32 * ks + 8 * quad];
      const bfrag al = *(const bfrag*)&tLo[(mb + l16) * T_STRIDE + 32 * ks + 8 * quad];
      #pragma unroll
      for (int n2 = 0; n2 < 2; ++n2){
        const int nt = 2 * wave + n2;
        const size_t off = ((size_t)((l * 8 + nt) * 4 + ks)) * 512 + lane * 8;
        const bfrag bh = *(const bfrag*)(Whi + off);
        const bfrag bl = *(const bfrag*)(Wlo + off);
        acc[l][n2] = __builtin_amdgcn_mfma_f32_16x16x32_bf16(ah, bh, acc[l][n2], 0, 0, 0);
        acc[l][n2] = __builtin_amdgcn_mfma_f32_16x16x32_bf16(al, bh, acc[l][n2], 0, 0, 0);
        acc[l][n2] = __builtin_amdgcn_mfma_f32_16x16x32_bf16(ah, bl, acc[l][n2], 0, 0, 0);
      }
    }
  }
}

// ================= kernel A: per-atom Z = W1 @ A (no bias) =================
__global__ __launch_bounds__(256, 4) void atoms_kernel(const float* __restrict__ A,
                                                       const short* __restrict__ W1hi,
                                                       const short* __restrict__ W1lo,
                                                       float* __restrict__ Z){
  __shared__ unsigned short aHi[32 * T_STRIDE];
  __shared__ unsigned short aLo[32 * T_STRIDE];
  const int n   = blockIdx.x;
  const int tid = threadIdx.x;
  const int f   = tid & 127, half = tid >> 7;
  const float* Ab = A + (size_t)n * NM * NF;

  const int m0 = half ? 13 : 0, m1 = half ? 25 : 13;
  for (int m = m0; m < m1; ++m){
    const float x = Ab[m * NF + f];
    const unsigned short h = bf16rn(x);
    aHi[m * T_STRIDE + f] = h;
    aLo[m * T_STRIDE + f] = bf16rn(x - bfhi_to_f(h));
  }
  if (half){
    for (int m = 25; m < 32; ++m){ aHi[m * T_STRIDE + f] = 0; aLo[m * T_STRIDE + f] = 0; }
  }
  __syncthreads();

  const int lane = tid & 63, wave = tid >> 6;
  f32x4 acc[5][2];
  #pragma unroll
  for (int l = 0; l < 5; ++l)
    #pragma unroll
    for (int n2 = 0; n2 < 2; ++n2)
      acc[l][n2] = f32x4{0.f, 0.f, 0.f, 0.f};

  mfma_gemm(aHi, aLo, W1hi, W1lo, lane, wave, acc);

  const int quad = lane >> 4, l16 = lane & 15;
  float* Zb = Z + (size_t)n * NM * NF;
  #pragma unroll
  for (int l = 0; l < 5; ++l)
    #pragma unroll
    for (int n2 = 0; n2 < 2; ++n2){
      const int col = 16 * (2 * wave + n2) + l16;
      #pragma unroll
      for (int r = 0; r < 4; ++r){
        if (r <= 2 * l){                       // compile-time prune
          const int row = 4 * quad + r;
          if (row <= 2 * l)                    // runtime lane mask
            Zb[(l * l + row) * NF + col] = acc[l][n2][r];
        }
      }
    }
}

// ================= TP accumulation (compile-time partitioned) =================
template<int CG>
__device__ __forceinline__ void tp_accum(const float* y2col /* = &y2_lds[g] */,
                                         const float bd[9], const float wp[NPATHS_C],
                                         float o[13]){
  constexpr int t0 = (CG == 0) ? 0 : TP_SPLIT;
  constexpr int t1 = (CG == 0) ? TP_SPLIT : TPN;
  constexpr int cbase = (CG == 0) ? 0 : 13;
  float y2b = 0.f;
  #pragma unroll
  for (int t = t0; t < t1; ++t){
    if (t == t0 || STP.e[t].b != STP.e[t-1].b)     // folds at compile time
      y2b = y2col[STP.e[t].b * Y_STRIDE];
    o[STP.e[t].c - cbase] = fmaf(STP.e[t].v * wp[STP.e[t].p],
                                 bd[STP.e[t].a] * y2b,
                                 o[STP.e[t].c - cbase]);
  }
}

// ================= kernel B: per-edge fused pipeline =================
__global__ __launch_bounds__(256, 4) void edge_kernel(const float* __restrict__ Z,
                                                      const int*   __restrict__ nbr,
                                                      const float* __restrict__ disp,
                                                      const float* __restrict__ b1,
                                                      const short* __restrict__ W2hi,
                                                      const short* __restrict__ W2lo,
                                                      const float* __restrict__ b2,
                                                      const float* __restrict__ W3,
                                                      const float* __restrict__ b3,
                                                      const float* __restrict__ wtp,
                                                      float* __restrict__ out){
  __shared__ unsigned short tHi[32 * T_STRIDE];
  __shared__ unsigned short tLo[32 * T_STRIDE];
  __shared__ float y2_lds[NM * Y_STRIDE];
  __shared__ float rad_s[NF];
  __shared__ float rw_lds[3 * NF];
  __shared__ float nbuf[2 * NF];
  __shared__ float y0buf[NF];

  const int e   = blockIdx.x;
  const int tid = threadIdx.x;
  const int f   = tid & 127, half = tid >> 7;
  const int i = nbr[2 * e], j = nbr[2 * e + 1];
  const float* Zi = Z + (size_t)i * NM * NF;
  const float* Zj = Z + (size_t)j * NM * NF;

  // ---- P1a: partial norm + radial basis ----
  const int m0 = half ? 13 : 0, m1 = half ? 25 : 13;
  float n2 = 0.f;
  for (int m = m0; m < m1; ++m){
    float v = Zi[m * NF + f] + Zj[m * NF + f];
    if (m == 0) v += b1[f];
    n2 = fmaf(v, v, n2);
    if (m == 0) y0buf[f] = v;
  }
  nbuf[half * NF + f] = n2;

  const float dx = disp[3 * e], dy = disp[3 * e + 1], dz = disp[3 * e + 2];
  const float r  = sqrtf(dx * dx + dy * dy + dz * dz + 1e-12f);
  if (!half){
    const float uc = r * 0.2f;
    const float den = fmaxf(1.f - uc * uc, 1e-9f);
    const float cut = (uc < 1.f) ? expf(1.f - 1.f / den) : 0.f;
    rad_s[f] = cosf((float)f * ((float)M_PI * 0.2f) * r) * cut;
  }
  __syncthreads();

  // ---- P1b: normalize + gated mish -> t (bf16 hi/lo) in LDS ----
  const float inv = 1.0f / sqrtf(nbuf[f] + nbuf[NF + f] + 1e-6f);
  const float s   = y0buf[f] * inv;
  const float sp  = fmaxf(s, 0.f) + log1pf(expf(-fabsf(s)));
  const float th  = tanhf(sp);
  const float sg  = 1.0f / (1.0f + expf(-s));
  const float dm  = th + s * (1.f - th * th) * sg;
  for (int m = m0; m < m1; ++m){
    float v = Zi[m * NF + f] + Zj[m * NF + f];     // L1-hot reload
    if (m == 0) v += b1[f];
    const float tv = (m == 0) ? (s * th) : (v * inv * dm);
    const unsigned short h = bf16rn(tv);
    tHi[m * T_STRIDE + f] = h;
    tLo[m * T_STRIDE + f] = bf16rn(tv - bfhi_to_f(h));
  }
  if (half){
    for (int m = 25; m < 32; ++m){ tHi[m * T_STRIDE + f] = 0; tLo[m * T_STRIDE + f] = 0; }
  }
  __syncthreads();

  // ---- P2: W2 GEMM (split-bf16 MFMA) ----
  const int lane = tid & 63, wave = tid >> 6;
  f32x4 acc[5][2];
  #pragma unroll
  for (int l = 0; l < 5; ++l)
    #pragma unroll
    for (int c = 0; c < 2; ++c)
      acc[l][c] = f32x4{0.f, 0.f, 0.f, 0.f};

  mfma_gemm(tHi, tLo, W2hi, W2lo, lane, wave, acc);

  const int quad = lane >> 4, l16 = lane & 15;
  #pragma unroll
  for (int l = 0; l < 5; ++l)
    #pragma unroll
    for (int c = 0; c < 2; ++c){
      const int col = 16 * (2 * wave + c) + l16;
      #pragma unroll
      for (int rr = 0; rr < 4; ++rr){
        if (rr <= 2 * l){
          const int row = 4 * quad + rr;
          if (row <= 2 * l)
            y2_lds[(l * l + row) * Y_STRIDE + col] = acc[l][c][rr];
        }
      }
    }
  __syncthreads();

  // ---- P3: residual (+b2) and radial @ W3 ----
  for (int m = m0; m < m1; ++m){
    const float t_re = bfhi_to_f(tHi[m * T_STRIDE + f]) + bfhi_to_f(tLo[m * T_STRIDE + f]);
    float v = y2_lds[m * Y_STRIDE + f] + t_re;
    if (m == 0) v += b2[f];
    y2_lds[m * Y_STRIDE + f] = v;
  }
  if (!half){
    float a0 = 0.f;
    for (int q = 0; q < NF; ++q) a0 = fmaf(rad_s[q], W3[(0 * NF + q) * NF + f], a0);
    rw_lds[f] = a0;
  } else {
    float a1 = 0.f, a2 = 0.f;
    for (int q = 0; q < NF; ++q){
      const float rq = rad_s[q];
      a1 = fmaf(rq, W3[(1 * NF + q) * NF + f], a1);
      a2 = fmaf(rq, W3[(2 * NF + q) * NF + f], a2);
    }
    rw_lds[NF + f] = a1;
    rw_lds[2 * NF + f] = a2;
  }
  __syncthreads();

  // ---- P4: tensor product + store ----
  const float ux = dx / r, uy = dy / r, uz = dz / r;
  const float s3 = 1.7320508075688772f;
  float bd[9];
  {
    const float rw0 = rw_lds[f], rw1 = rw_lds[NF + f], rw2 = rw_lds[2 * NF + f];
    bd[0] = rw0 + b3[f];
    bd[1] = uy * rw1;
    bd[2] = uz * rw1;
    bd[3] = ux * rw1;
    bd[4] = (s3 * ux * uy) * rw2;
    bd[5] = (s3 * uy * uz) * rw2;
    bd[6] = (0.5f * (3.f * uz * uz - 1.f)) * rw2;
    bd[7] = (s3 * ux * uz) * rw2;
    bd[8] = (0.5f * s3 * (ux * ux - uy * uy)) * rw2;
  }
  float wp[NPATHS_C];
  #pragma unroll
  for (int p = 0; p < NPATHS_C; ++p) wp[p] = wtp[p * NF + f];

  float o[13];
  #pragma unroll
  for (int k = 0; k < 13; ++k) o[k] = 0.f;

  float* ob = out + (size_t)e * NM * NF;
  if (!half){
    tp_accum<0>(&y2_lds[f], bd, wp, o);
    #pragma unroll
    for (int k = 0; k < 13; ++k) ob[k * NF + f] = o[k];
  } else {
    tp_accum<1>(&y2_lds[f], bd, wp, o);
    #pragma unroll
    for (int k = 0; k < 12; ++k) ob[(13 + k) * NF + f] = o[k];
  }
}

} // anonymous namespace

extern "C" void kernel_launch(void* const* d_in, const int* in_sizes, int n_in,
                              void* d_out, int out_size, void* d_ws, size_t ws_size,
                              hipStream_t stream) {
  (void)n_in; (void)out_size;
  const float* A    = (const float*)d_in[0];
  const int*   nbr  = (const int*)  d_in[1];
  const float* disp = (const float*)d_in[2];
  const float* W1   = (const float*)d_in[3];
  const float* b1   = (const float*)d_in[4];
  const float* W2   = (const float*)d_in[5];
  const float* b2   = (const float*)d_in[6];
  const float* W3   = (const float*)d_in[7];
  const float* b3   = (const float*)d_in[8];
  const float* wtp  = (const float*)d_in[9];
  float* out = (float*)d_out;

  const int n_atoms = in_sizes[0] / (NM * NF);
  const int n_edges = in_sizes[1] / 2;

  // ws layout: 4 swizzled weight arrays (163840 B each) + Z (n_atoms*25*128 fp32)
  const size_t wsz   = (size_t)5 * 8 * 4 * 64 * 8 * sizeof(short);  // 163840 B
  const size_t zoff  = 4 * wsz;
  const size_t need  = zoff + (size_t)n_atoms * NM * NF * sizeof(float);
  if (ws_size < need) return;

  short* W1hi = (short*)((char*)d_ws + 0 * wsz);
  short* W1lo = (short*)((char*)d_ws + 1 * wsz);
  short* W2hi = (short*)((char*)d_ws + 2 * wsz);
  short* W2lo = (short*)((char*)d_ws + 3 * wsz);
  float* Z    = (float*)((char*)d_ws + zoff);

  prep_kernel<<<dim3(80), dim3(256), 0, stream>>>(W1, W2, W1hi, W1lo, W2hi, W2lo);
  atoms_kernel<<<dim3(n_atoms), dim3(256), 0, stream>>>(A, W1hi, W1lo, Z);
  edge_kernel<<<dim3(n_edges), dim3(256), 0, stream>>>(Z, nbr, disp, b1, W2hi, W2lo,
                                                       b2, W3, b3, wtp, out);
}